// Round 5
// baseline (381.637 us; speedup 1.0000x reference)
//
#include <hip/hip_runtime.h>
#include <math.h>

#define IMG   512
#define OUTD  502            // 512 - 10
#define NBC   48             // 16*3
#define TH    64             // output tile rows
#define TW    32             // output tile cols
#define IN_ROWS (TH + 10)    // 74
#define HBW   32
#define GY    8              // ceil(502/64)
#define GZ    16             // 502/32 rounded up
#define TOTAL_BLOCKS (NBC * GY * GZ)   // 6144

struct WParams { float w[11]; };

// ws layout: [0..3] uint min_key, [4..7] uint max_key, [8..15] double sum,
//            [16..19] uint done-counter

__device__ __forceinline__ unsigned enc_key(float f) {
    unsigned u = __float_as_uint(f);
    return (u & 0x80000000u) ? ~u : (u | 0x80000000u);
}
__device__ __forceinline__ float dec_key(unsigned k) {
    unsigned u = (k & 0x80000000u) ? (k ^ 0x80000000u) : ~k;
    return __uint_as_float(u);
}

__global__ __launch_bounds__(256) void minmax_kernel(const float4* __restrict__ x,
                                                     int n4, unsigned* wsi) {
    float lmin = INFINITY, lmax = -INFINITY;
    for (int i = blockIdx.x * blockDim.x + threadIdx.x; i < n4;
         i += gridDim.x * blockDim.x) {
        float4 v = x[i];
        lmin = fminf(lmin, fminf(fminf(v.x, v.y), fminf(v.z, v.w)));
        lmax = fmaxf(lmax, fmaxf(fmaxf(v.x, v.y), fmaxf(v.z, v.w)));
    }
    for (int o = 32; o; o >>= 1) {
        lmin = fminf(lmin, __shfl_xor(lmin, o));
        lmax = fmaxf(lmax, __shfl_xor(lmax, o));
    }
    __shared__ float smin[4], smax[4];
    int tid = threadIdx.x;
    if ((tid & 63) == 0) { smin[tid >> 6] = lmin; smax[tid >> 6] = lmax; }
    __syncthreads();
    if (tid == 0) {
        float m0 = fminf(fminf(smin[0], smin[1]), fminf(smin[2], smin[3]));
        float m1 = fmaxf(fmaxf(smax[0], smax[1]), fmaxf(smax[2], smax[3]));
        atomicMin(&wsi[0], enc_key(m0));
        atomicMax(&wsi[1], enc_key(m1));
    }
}

// Horizontal 11-tap conv of 4 adjacent columns starting at register offset J0.
// Indices are all compile-time; clamp (only active for J0=4, cols 2,3) keeps
// them in [0,15] — those outputs are garbage-but-finite and never needed.
template<int J0>
__device__ __forceinline__ void hconv(const float* __restrict__ w,
                                      const float xr[16], const float yr[16],
                                      float acc[5][4]) {
    float xx[16], yy[16], xy[16];
    #pragma unroll
    for (int e = 0; e < 16; e++) {
        xx[e] = xr[e] * xr[e];
        yy[e] = yr[e] * yr[e];
        xy[e] = xr[e] * yr[e];
    }
    #pragma unroll
    for (int k = 0; k < 11; k++) {
        float wk = w[k];
        #pragma unroll
        for (int j = 0; j < 4; j++) {
            int i = J0 + j + k;
            if (i > 15) i = 15;
            acc[0][j] += wk * xr[i];
            acc[1][j] += wk * yr[i];
            acc[2][j] += wk * xx[i];
            acc[3][j] += wk * yy[i];
            acc[4][j] += wk * xy[i];
        }
    }
}

__global__ __launch_bounds__(256) void ssim_kernel(const float* __restrict__ x,
                                                   const float* __restrict__ y,
                                                   const unsigned* __restrict__ wsi,
                                                   double* __restrict__ wsum,
                                                   unsigned* __restrict__ wcount,
                                                   float* __restrict__ out,
                                                   WParams P) {
    // LDS: 5*74*32*4 = 47360 B -> 3 blocks/CU (12 waves)
    __shared__ __align__(16) float hb[5 * IN_ROWS * HBW];
    __shared__ float wpart[4];

    const int tid = threadIdx.x;
    const int bc  = blockIdx.x;
    const int oy0 = blockIdx.y * TH;
    const int ox0 = blockIdx.z * TW;
    const float* xb = x + (size_t)bc * IMG * IMG;
    const float* yb = y + (size_t)bc * IMG * IMG;

    // ---- horizontal pass: read 16 floats/image straight from global (L2/L3-warm)
    for (int idx = tid; idx < IN_ROWS * 8; idx += 256) {
        int r = idx >> 3, g = idx & 7;
        int gy   = min(oy0 + r, IMG - 1);
        int col0 = ox0 + 4 * g;
        int gx0  = min(col0, IMG - 16);
        const float* rx = xb + gy * IMG + gx0;
        const float* ry = yb + gy * IMG + gx0;
        float xr[16], yr[16];
        #pragma unroll
        for (int q = 0; q < 4; q++) {
            float4 a = *(const float4*)(rx + 4 * q);
            float4 b = *(const float4*)(ry + 4 * q);
            xr[4*q] = a.x; xr[4*q+1] = a.y; xr[4*q+2] = a.z; xr[4*q+3] = a.w;
            yr[4*q] = b.x; yr[4*q+1] = b.y; yr[4*q+2] = b.z; yr[4*q+3] = b.w;
        }
        float acc[5][4];
        #pragma unroll
        for (int ch = 0; ch < 5; ch++)
            #pragma unroll
            for (int j = 0; j < 4; j++) acc[ch][j] = 0.f;
        if (col0 <= IMG - 16) hconv<0>(P.w, xr, yr, acc);
        else                  hconv<4>(P.w, xr, yr, acc);   // only last col-tile, g>=5
        #pragma unroll
        for (int ch = 0; ch < 5; ch++) {
            float4 v = make_float4(acc[ch][0], acc[ch][1], acc[ch][2], acc[ch][3]);
            *(float4*)(hb + (ch * IN_ROWS + r) * HBW + 4 * g) = v;
        }
    }

    // constants (uniform; latency hidden under the barrier)
    float fmin_v = dec_key(wsi[0]);
    float fmax_v = dec_key(wsi[1]);
    float L  = fmax_v - fmin_v;
    float C1 = 0.01f * L; C1 *= C1;
    float C2 = 0.03f * L; C2 *= C2;

    __syncthreads();

    // ---- vertical pass: each thread 4 output rows x 2 cols, 14-row slide
    const int q  = tid & 15;
    const int rr = tid >> 4;
    const int r0 = 4 * rr;
    const int c  = 2 * q;

    float2 acc[5][4];
    #pragma unroll
    for (int ch = 0; ch < 5; ch++)
        #pragma unroll
        for (int o = 0; o < 4; o++) { acc[ch][o].x = 0.f; acc[ch][o].y = 0.f; }

    #pragma unroll
    for (int k = 0; k < 14; k++) {
        #pragma unroll
        for (int ch = 0; ch < 5; ch++) {
            float2 v = *(const float2*)(hb + (ch * IN_ROWS + r0 + k) * HBW + c);
            #pragma unroll
            for (int o = 0; o < 4; o++) {
                int t = k - o;                 // compile-time after unroll
                if (t >= 0 && t <= 10) {
                    acc[ch][o].x += P.w[t] * v.x;
                    acc[ch][o].y += P.w[t] * v.y;
                }
            }
        }
    }

    float lsum = 0.f;
    #pragma unroll
    for (int o = 0; o < 4; o++) {
        int oy = oy0 + r0 + o;
        #pragma unroll
        for (int cc = 0; cc < 2; cc++) {
            int ox = ox0 + c + cc;
            if (oy < OUTD && ox < OUTD) {
                float m1  = cc ? acc[0][o].y : acc[0][o].x;
                float m2  = cc ? acc[1][o].y : acc[1][o].x;
                float e11 = cc ? acc[2][o].y : acc[2][o].x;
                float e22 = cc ? acc[3][o].y : acc[3][o].x;
                float e12 = cc ? acc[4][o].y : acc[4][o].x;
                float m1s = m1 * m1, m2s = m2 * m2, m12 = m1 * m2;
                float v1  = 2.f * (e12 - m12) + C2;
                float v2  = (e11 - m1s) + (e22 - m2s) + C2;
                float num = (2.f * m12 + C1) * v1;
                float den = (m1s + m2s + C1) * v2;
                float rc  = __builtin_amdgcn_rcpf(den);
                rc = rc * (2.f - den * rc);   // one Newton step
                lsum += num * rc;
            }
        }
    }

    for (int o = 32; o; o >>= 1) lsum += __shfl_xor(lsum, o);
    if ((tid & 63) == 0) wpart[tid >> 6] = lsum;
    __syncthreads();
    if (tid == 0) {
        double t = (double)wpart[0] + (double)wpart[1] +
                   (double)wpart[2] + (double)wpart[3];
        atomicAdd(wsum, t);
        __threadfence();                       // publish before signaling done
        unsigned done = atomicAdd(wcount, 1u);
        if (done == TOTAL_BLOCKS - 1) {
            __threadfence();
            double total = atomicAdd(wsum, 0.0);   // device-scope read of final sum
            const double count = (double)NBC * OUTD * OUTD;  // 12,096,192
            out[0] = (float)(-total / count);
        }
    }
}

extern "C" void kernel_launch(void* const* d_in, const int* in_sizes, int n_in,
                              void* d_out, int out_size, void* d_ws, size_t ws_size,
                              hipStream_t stream) {
    (void)n_in; (void)out_size; (void)ws_size;
    const float* y_pred = (const float*)d_in[0];
    const float* y_true = (const float*)d_in[1];
    float* out = (float*)d_out;

    unsigned* wsi    = (unsigned*)d_ws;
    double*   wsum   = (double*)((char*)d_ws + 8);
    unsigned* wcount = (unsigned*)((char*)d_ws + 16);

    // Gaussian window in fp64, normalized, cast to fp32 — matches NumPy ref
    WParams P;
    {
        double g[11], s = 0.0;
        for (int i = 0; i < 11; i++) {
            double d = (double)(i - 5);
            g[i] = exp(-(d * d) / (2.0 * 1.5 * 1.5));
            s += g[i];
        }
        for (int i = 0; i < 11; i++) P.w[i] = (float)(g[i] / s);
    }

    // init: min_key = 0xFFFFFFFF, max_key = 0, sum = 0.0, counter = 0
    hipMemsetAsync(d_ws, 0xFF, 4, stream);
    hipMemsetAsync((char*)d_ws + 4, 0, 16, stream);

    int n4 = in_sizes[0] / 4;
    minmax_kernel<<<2048, 256, 0, stream>>>((const float4*)y_pred, n4, wsi);

    dim3 grid(NBC, GY, GZ);  // 48 x 8 x 16
    ssim_kernel<<<grid, 256, 0, stream>>>(y_pred, y_true, wsi, wsum, wcount, out, P);
}